// Round 14
// baseline (725.673 us; speedup 1.0000x reference)
//
#include <hip/hip_runtime.h>
#include <hip/hip_bf16.h>

typedef unsigned short u16;
typedef __attribute__((ext_vector_type(4))) float f32x4;
typedef __attribute__((ext_vector_type(4))) int i32x4;
typedef __attribute__((ext_vector_type(8))) short bf16x8;

#define NIT 4
#define NCLS 21
#define BS 8
#define CIN 2048
#define COUT 1024
#define WH 1024

#define SX 32.0f
#define SW 3200.0f
#define INVS (1.0f / (SX * SW))

__device__ __forceinline__ u16 f2bf(float f) {
  union { float f; unsigned u; } v; v.f = f;
  unsigned r = v.u + 0x7fffu + ((v.u >> 16) & 1u);
  return (u16)(r >> 16);
}
__device__ __forceinline__ float bf2f(u16 h) {
  union { unsigned u; float f; } v; v.u = ((unsigned)h) << 16;
  return v.f;
}
__device__ __forceinline__ unsigned q8u(float v, float s) {
  float x = v * s;
  x = fminf(fmaxf(x, -127.f), 127.f);
  return (unsigned)(unsigned char)(signed char)__float2int_rn(x);
}

#define GLDS16(gp, lp) __builtin_amdgcn_global_load_lds( \
    (const __attribute__((address_space(1))) unsigned int*)(gp), \
    (__attribute__((address_space(3))) unsigned int*)(lp), 16, 0, 0)

// ---------------- prep: conv2d_w f32 -> wt [it][tap][co][ci] int8, packed u32 stores
__global__ void prep_w_kernel(const float* __restrict__ w, unsigned* __restrict__ wt4) {
  int it = blockIdx.x >> 10, co = blockIdx.x & 1023;
  const f32x4* src4 = (const f32x4*)(w + (size_t)(it * 1024 + co) * (CIN * 9));
  __shared__ float ls[9216];
  int t = threadIdx.x;
  for (int chunk = 0; chunk < 2; ++chunk) {
    for (int i = t; i < 2304; i += 256)
      *(f32x4*)&ls[i * 4] = src4[chunk * 2304 + i];
    __syncthreads();
    float r[36];
    #pragma unroll
    for (int j = 0; j < 9; ++j)
      *(f32x4*)&r[j * 4] = *(const f32x4*)&ls[t * 36 + j * 4];
    #pragma unroll
    for (int tap = 0; tap < 9; ++tap) {
      unsigned pk = q8u(r[tap], SW)
                  | (q8u(r[9 + tap], SW) << 8)
                  | (q8u(r[18 + tap], SW) << 16)
                  | (q8u(r[27 + tap], SW) << 24);
      wt4[((((size_t)(it * 9 + tap) * 1024 + co) * CIN + chunk * 1024) >> 2) + t] = pk;
    }
    __syncthreads();
  }
}

// ---------------- prep: x f32 -> xT [b][p][ci] int8, packed u32 stores
__global__ void prep_x_kernel(const float* __restrict__ x, unsigned* __restrict__ xT4) {
  int bid = blockIdx.x;
  int pT = bid & 15, ciT = (bid >> 4) & 31, b = bid >> 9;
  __shared__ float ls[64][65];
  int t = threadIdx.x;
  int tr = t >> 6, tc = t & 63;
  const float* xp = x + ((size_t)b * CIN + ciT * 64) * WH + pT * 64;
  #pragma unroll
  for (int r = 0; r < 16; ++r) {
    int ci = r * 4 + tr;
    ls[ci][tc] = xp[(size_t)ci * WH + tc];
  }
  __syncthreads();
  unsigned* xtp = xT4 + ((((size_t)b * WH + pT * 64) * CIN + ciT * 64) >> 2);
  #pragma unroll
  for (int r = 0; r < 4; ++r) {
    int p = r * 16 + (t >> 4);
    int ci0 = (t & 15) * 4;
    unsigned pk = q8u(ls[ci0][p], SX)
                | (q8u(ls[ci0 + 1][p], SX) << 8)
                | (q8u(ls[ci0 + 2][p], SX) << 16)
                | (q8u(ls[ci0 + 3][p], SX) << 24);
    xtp[(size_t)p * (CIN >> 2) + (t & 15)] = pk;
  }
}

// ---------------- norm: diffW -> normT[m][n] bf16, vectorized
__global__ void norm_kernel(const float* __restrict__ diffW, u16* __restrict__ normT) {
  int b = blockIdx.x >> 10, m = blockIdx.x & 1023;
  int t = threadIdx.x;
  const f32x4* row4 = (const f32x4*)(diffW + (((size_t)(b * 1024 + m)) << 10));
  f32x4 vv = row4[t];
  float s = 0.f;
  #pragma unroll
  for (int i = 0; i < 4; ++i) {
    vv[i] = (vv[i] > 0.8f) ? vv[i] : 0.f;
    s += vv[i];
  }
  #pragma unroll
  for (int off = 1; off < 64; off <<= 1) s += __shfl_xor(s, off);
  __shared__ float red[4];
  if ((t & 63) == 0) red[t >> 6] = s;
  __syncthreads();
  float inv = 1.f / (red[0] + red[1] + red[2] + red[3]);
  ushort4 o;
  o.x = f2bf(vv[0] * inv); o.y = f2bf(vv[1] * inv);
  o.z = f2bf(vv[2] * inv); o.w = f2bf(vv[3] * inv);
  *((ushort4*)(normT + (((size_t)(b * 1024 + m)) << 10)) + t) = o;
}

__global__ void zero_kernel(float* p) { p[threadIdx.x] = 0.f; }

// ================ conv implicit GEMM, 128^2 tile, INT8 MFMA, 2 blocks/CU
// 64 KiB LDS -> TWO independent blocks per CU (same 2 waves/SIMD but from
// independent barriers: one block's stage/drain is covered by the other's
// MFMA). Finer nt granularity (y-range 4) sharpens tap-skip (-5.5% work).
// Schedule = proven single-barrier K=128: A&B staged at +1, end-of-j vmcnt(0).
__global__ __launch_bounds__(256, 2)
void conv8_kernel(const signed char* __restrict__ wt, const signed char* __restrict__ xT,
                  const float* __restrict__ bias, const signed char* __restrict__ zpage,
                  u16* __restrict__ out_all) {
  const int bid = blockIdx.x;
  const int b = bid & 7;
  const int mt = (bid >> 3) & 7;
  const int rest = bid >> 6;
  const int it = rest >> 3, nt = rest & 7;
  const int M0 = mt * 128, N0 = nt * 128;
  const int tid = threadIdx.x, wave = tid >> 6, lane = tid & 63;
  const int wm = wave >> 1, wn = wave & 1;         // 2 x 2 wave grid, 64x64 each

  const int dil = 6 * (it + 1);
  const int tlo = (4 * nt + 3 < dil) ? 3 : 0;
  const int thi = (4 * nt + dil >= 32) ? 6 : 9;
  const int NT = (thi - tlo) * 16;                 // K-tiles of 128 i8

  __shared__ char lds[2][2][128][128];             // 64 KiB

  const signed char* Aglob = wt + (size_t)it * 9 * COUT * CIN;
  const signed char* Bglob = xT + (size_t)b * WH * CIN;

  const int srow = lane >> 3;
  const int scol16 = (lane & 7) ^ srow;

  const signed char* abase[4]; const signed char* bbase[4];
  unsigned long long vmask = 0ull;
  #pragma unroll
  for (int r = 0; r < 4; ++r) {
    int arow = M0 + r * 32 + wave * 8 + srow;
    abase[r] = Aglob + (size_t)arow * CIN + scol16 * 16;
    int n = N0 + r * 32 + wave * 8 + srow;
    bbase[r] = Bglob + (size_t)n * CIN + scol16 * 16;
    int py0 = n >> 5, px0 = n & 31;
    #pragma unroll
    for (int tap = 0; tap < 9; ++tap) {
      int t3 = (tap * 11) >> 5;
      int py = py0 + (t3 - 1) * dil;
      int px = px0 + (tap - t3 * 3 - 1) * dil;
      if (((unsigned)py < 32u) && ((unsigned)px < 32u))
        vmask |= (1ull << (r * 9 + tap));
    }
  }
  const signed char* zp = zpage + scol16 * 16;

  auto stageA = [&](int jj, int bb) {
    if (jj >= NT) return;
    int tap = tlo + (jj >> 4);
    size_t uoff = (size_t)tap * (COUT * CIN) + (size_t)((jj & 15) << 7);
    #pragma unroll
    for (int r = 0; r < 4; ++r)
      GLDS16(abase[r] + uoff, &lds[bb][0][r * 32 + wave * 8][0]);
  };
  auto stageB = [&](int jj, int bb) {
    if (jj >= NT) return;
    int tap = tlo + (jj >> 4);
    int t3 = (tap * 11) >> 5;
    ptrdiff_t toff = (ptrdiff_t)(((t3 - 1) * 32 + (tap - t3 * 3 - 1)) * dil) * CIN
                   + (ptrdiff_t)((jj & 15) << 7);
    #pragma unroll
    for (int r = 0; r < 4; ++r) {
      bool valid = (vmask >> (r * 9 + tap)) & 1ull;
      const signed char* src = valid ? (bbase[r] + toff) : zp;
      GLDS16(src, &lds[bb][1][r * 32 + wave * 8][0]);
    }
  };

  i32x4 acc[4][4] = {};

  const int l15 = lane & 15;
  const int colx[2] = { (((lane >> 4) ^ (lane & 7)) * 16),
                        (((4 + (lane >> 4)) ^ (lane & 7)) * 16) };
  const int arow_byte = (wm * 64 + l15) * 128;
  const int brow_byte = (wn * 64 + l15) * 128;

  stageA(0, 0); stageB(0, 0);
  __builtin_amdgcn_sched_barrier(0);
  asm volatile("s_waitcnt vmcnt(0)" ::: "memory");
  __builtin_amdgcn_s_barrier();
  __builtin_amdgcn_sched_barrier(0);

  for (int j = 0; j < NT; ++j) {
    const int p2 = j & 1;
    const char* Ab = (const char*)&lds[p2][0][0][0];
    const char* Bb = (const char*)&lds[p2][1][0][0];

    i32x4 bfr[4][2];
    #pragma unroll
    for (int nf = 0; nf < 4; ++nf) {
      bfr[nf][0] = *(const i32x4*)(Bb + brow_byte + nf * 2048 + colx[0]);
      bfr[nf][1] = *(const i32x4*)(Bb + brow_byte + nf * 2048 + colx[1]);
    }
    stageA(j + 1, p2 ^ 1);
    stageB(j + 1, p2 ^ 1);

    __builtin_amdgcn_s_setprio(1);
    #pragma unroll
    for (int m = 0; m < 4; ++m) {
      i32x4 a0 = *(const i32x4*)(Ab + arow_byte + m * 2048 + colx[0]);
      i32x4 a1 = *(const i32x4*)(Ab + arow_byte + m * 2048 + colx[1]);
      #pragma unroll
      for (int nf = 0; nf < 4; ++nf) {
        acc[m][nf] = __builtin_amdgcn_mfma_i32_16x16x64_i8(a0, bfr[nf][0], acc[m][nf], 0, 0, 0);
        acc[m][nf] = __builtin_amdgcn_mfma_i32_16x16x64_i8(a1, bfr[nf][1], acc[m][nf], 0, 0, 0);
      }
    }
    __builtin_amdgcn_s_setprio(0);
    __builtin_amdgcn_sched_barrier(0);
    asm volatile("s_waitcnt vmcnt(0)" ::: "memory");
    __builtin_amdgcn_s_barrier();
    __builtin_amdgcn_sched_barrier(0);
  }

  u16* outp = out_all + (size_t)(it * BS + b) * COUT * WH;
  const float* bias_it = bias + it * COUT;
  #pragma unroll
  for (int mf = 0; mf < 4; ++mf)
    #pragma unroll
    for (int nf = 0; nf < 4; ++nf) {
      int col = N0 + wn * 64 + nf * 16 + l15;
      #pragma unroll
      for (int r = 0; r < 4; ++r) {
        int row = M0 + wm * 64 + mf * 16 + (lane >> 4) * 4 + r;
        float v = (float)acc[mf][nf][r] * INVS + bias_it[row];
        outp[((size_t)row << 10) + col] = f2bf(v);
      }
    }
}

// ---------------- P[it,b,c,k] = sum_d w1[it,c,d]*out[it,b,d,k]  (256 blocks x 512 thr)
__global__ __launch_bounds__(512, 2)
void p_kernel(const u16* __restrict__ out_all, const float* __restrict__ w1,
              float* __restrict__ P) {
  int bidx = blockIdx.x;
  int kch = bidx & 7, sl = bidx >> 3;   // sl = it*8+b
  int it = sl >> 3;
  int t = threadIdx.x;
  int wave = t >> 6, lane = t & 63;
  int g = wave & 3;
  int k = kch * 128 + (wave >> 2) * 64 + lane;
  __shared__ float w1f[21][512];
  const u16* op = out_all + ((size_t)sl << 20) + k;
  const float* w1p = w1 + (size_t)it * NCLS * 1024;
  float acc[6] = {0.f, 0.f, 0.f, 0.f, 0.f, 0.f};
  const int cbase = g * 6;
  for (int h = 0; h < 2; ++h) {
    __syncthreads();
    for (int l = t; l < 21 * 128; l += 512) {
      int c = l >> 7, qq = l & 127;
      *(f32x4*)&w1f[c][qq * 4] = *(const f32x4*)(w1p + (size_t)c * 1024 + h * 512 + qq * 4);
    }
    __syncthreads();
    const u16* oph = op + ((size_t)(h * 512) << 10);
    #pragma unroll 4
    for (int dq = 0; dq < 128; ++dq) {
      float vv[4];
      #pragma unroll
      for (int j = 0; j < 4; ++j) vv[j] = bf2f(oph[(size_t)(dq * 4 + j) << 10]);
      #pragma unroll
      for (int cj = 0; cj < 6; ++cj) {
        int c = cbase + cj; if (c > 20) c = 20;
        f32x4 w4 = *(const f32x4*)&w1f[c][dq * 4];
        acc[cj] = fmaf(w4[0], vv[0], acc[cj]);
        acc[cj] = fmaf(w4[1], vv[1], acc[cj]);
        acc[cj] = fmaf(w4[2], vv[2], acc[cj]);
        acc[cj] = fmaf(w4[3], vv[3], acc[cj]);
      }
    }
  }
  float* Pp = P + (((size_t)sl * NCLS) << 10) + k;
  #pragma unroll
  for (int cj = 0; cj < 6; ++cj) {
    int c = cbase + cj;
    if (c < NCLS) Pp[(size_t)c << 10] = acc[cj];
  }
}

// ---------------- Psum[b][c][k] = sum_it P[it,b,c,k]  (bf16)
__global__ void psum_kernel(const float* __restrict__ P, u16* __restrict__ Psum) {
  int idx = blockIdx.x * 256 + threadIdx.x;   // 21504 = 8*21*128
  int k8 = idx & 127;
  int c = (idx >> 7) % 21;
  int b = idx / (21 * 128);
  float s[8] = {};
  #pragma unroll
  for (int it = 0; it < 4; ++it) {
    const float* pp = P + ((((size_t)(it * 8 + b)) * NCLS + c) << 10) + k8 * 8;
    f32x4 a0 = *(const f32x4*)pp;
    f32x4 a1 = *(const f32x4*)(pp + 4);
    s[0] += a0[0]; s[1] += a0[1]; s[2] += a0[2]; s[3] += a0[3];
    s[4] += a1[0]; s[5] += a1[1]; s[6] += a1[2]; s[7] += a1[3];
  }
  bf16x8 pv;
  #pragma unroll
  for (int j = 0; j < 8; ++j) pv[j] = (short)f2bf(s[j]);
  *(bf16x8*)(Psum + (((size_t)(b * NCLS + c)) << 10) + k8 * 8) = pv;
}

// ---------------- weicum2a: partial o2sum over k-chunk (128 blocks)
__global__ __launch_bounds__(256, 4)
void weicum2a_kernel(const u16* __restrict__ Psum, const u16* __restrict__ normT,
                     float* __restrict__ o2part) {
  int bidx = blockIdx.x;     // b(8) x mch(4) x kch(4)
  int kch = bidx & 3, mch = (bidx >> 2) & 3, b = bidx >> 4;
  int t = threadIdx.x;
  __shared__ u16 ps[21][256];
  for (int l = t; l < 21 * 32; l += 256) {
    int c = l >> 5, q = l & 31;
    *(bf16x8*)&ps[c][q * 8] =
        *(const bf16x8*)(Psum + (((size_t)(b * NCLS + c)) << 10) + kch * 256 + q * 8);
  }
  __syncthreads();
  int m = mch * 256 + t;
  const u16* nr = normT + ((size_t)(b * 1024 + m)) * 1024 + kch * 256;
  float acc[NCLS];
  #pragma unroll
  for (int c = 0; c < NCLS; ++c) acc[c] = 0.f;
  for (int oct = 0; oct < 32; ++oct) {
    bf16x8 nv = *(const bf16x8*)(nr + oct * 8);
    float nf[8];
    #pragma unroll
    for (int j = 0; j < 8; ++j) nf[j] = bf2f((u16)nv[j]);
    #pragma unroll
    for (int c = 0; c < NCLS; ++c) {
      bf16x8 pv = *(const bf16x8*)&ps[c][oct * 8];
      #pragma unroll
      for (int j = 0; j < 8; ++j) acc[c] = fmaf(nf[j], bf2f((u16)pv[j]), acc[c]);
    }
  }
  float* op = o2part + (size_t)bidx * NCLS * 256;
  #pragma unroll
  for (int c = 0; c < NCLS; ++c) op[c * 256 + t] = acc[c];
}

// ---------------- weicum2b: reduce partials + double softmax -> wc_out, inp
__global__ void weicum2b_kernel(const float* __restrict__ o2part, const float* __restrict__ b1,
                                float* __restrict__ wc_out, float* __restrict__ inp) {
  int bidx = blockIdx.x;  // 32 = b(8) x mch(4)
  int mch = bidx & 3, b = bidx >> 2;
  int t = threadIdx.x;
  int m = mch * 256 + t;
  float acc[NCLS];
  #pragma unroll
  for (int c = 0; c < NCLS; ++c) {
    float s = 0.f;
    #pragma unroll
    for (int kch = 0; kch < 4; ++kch)
      s += o2part[((size_t)((b * 4 + mch) * 4 + kch) * NCLS + c) * 256 + t];
    acc[c] = s;
  }
  float mx = -1e30f;
  #pragma unroll
  for (int c = 0; c < NCLS; ++c) {
    float bs = 0.f;
    #pragma unroll
    for (int itp = 0; itp < NIT; ++itp) bs += b1[itp * NCLS + c];
    acc[c] = (acc[c] + bs) * 0.25f;
    mx = fmaxf(mx, acc[c]);
  }
  float s = 0.f;
  #pragma unroll
  for (int c = 0; c < NCLS; ++c) { acc[c] = expf(acc[c] - mx); s += acc[c]; }
  float inv = 1.f / s;
  float* wp = wc_out + (((size_t)b * NCLS) << 10) + m;
  float mx2 = -1e30f;
  #pragma unroll
  for (int c = 0; c < NCLS; ++c) {
    acc[c] *= inv;
    wp[(size_t)c << 10] = acc[c];
    mx2 = fmaxf(mx2, acc[c]);
  }
  float s2 = 0.f;
  #pragma unroll
  for (int c = 0; c < NCLS; ++c) { acc[c] = expf(acc[c] - mx2); s2 += acc[c]; }
  float inv2 = 1.f / s2;
  float* ip = inp + (((size_t)b * NCLS) << 10) + m;
  #pragma unroll
  for (int c = 0; c < NCLS; ++c) ip[(size_t)c << 10] = acc[c] * inv2;
}

// ---------------- per-(it,b,c): wei = softmax_n(inp*exp(pw)); pred = sum_n wei*P + b1
__global__ void weipred_kernel(const float* __restrict__ inp, const float* __restrict__ proj,
                               const float* __restrict__ pool_w, const float* __restrict__ b1,
                               float* __restrict__ pred, float* __restrict__ wei_out) {
  int bid = blockIdx.x;                 // it*168 + b*21 + c
  int it = bid / 168, r = bid % 168;
  int b = r / NCLS, c = r % NCLS;
  int t = threadIdx.x;
  float scale = expf(pool_w[it * NCLS + c]);
  const float* ip = inp + ((size_t)(b * NCLS + c)) * 1024;
  float v[4]; float mx = -1e30f;
  #pragma unroll
  for (int i = 0; i < 4; ++i) { v[i] = ip[t + i * 256] * scale; mx = fmaxf(mx, v[i]); }
  __shared__ float red[4];
  #pragma unroll
  for (int off = 1; off < 64; off <<= 1) mx = fmaxf(mx, __shfl_xor(mx, off));
  if ((t & 63) == 0) red[t >> 6] = mx;
  __syncthreads();
  mx = fmaxf(fmaxf(red[0], red[1]), fmaxf(red[2], red[3]));
  __syncthreads();
  float s = 0.f;
  #pragma unroll
  for (int i = 0; i < 4; ++i) { v[i] = expf(v[i] - mx); s += v[i]; }
  #pragma unroll
  for (int off = 1; off < 64; off <<= 1) s += __shfl_xor(s, off);
  if ((t & 63) == 0) red[t >> 6] = s;
  __syncthreads();
  s = red[0] + red[1] + red[2] + red[3];
  float inv = 1.f / s;
  __syncthreads();
  const float* pj = proj + (((size_t)(it * BS + b)) * NCLS + c) * 1024;
  float ps = 0.f;
  #pragma unroll
  for (int i = 0; i < 4; ++i) {
    float wv = v[i] * inv;
    ps += wv * pj[t + i * 256];
    if (it == NIT - 1) wei_out[((size_t)(b * NCLS + c)) * 1024 + t + i * 256] = wv;
  }
  #pragma unroll
  for (int off = 1; off < 64; off <<= 1) ps += __shfl_xor(ps, off);
  if ((t & 63) == 0) red[t >> 6] = ps;
  __syncthreads();
  if (t == 0) pred[bid] = red[0] + red[1] + red[2] + red[3] + b1[it * NCLS + c];
}

// ---------------- prob = sigmoid(mean_it pred)
__global__ void prob_kernel(const float* __restrict__ pred, float* __restrict__ out) {
  int i = threadIdx.x;
  if (i < BS * NCLS) {
    float s = 0.f;
    #pragma unroll
    for (int it = 0; it < NIT; ++it) s += pred[it * BS * NCLS + i];
    s *= 0.25f;
    out[i] = 1.f / (1.f + expf(-s));
  }
}

extern "C" void kernel_launch(void* const* d_in, const int* in_sizes, int n_in,
                              void* d_out, int out_size, void* d_ws, size_t ws_size,
                              hipStream_t stream) {
  const float* x        = (const float*)d_in[0];
  const float* diffW    = (const float*)d_in[1];
  const float* conv2d_w = (const float*)d_in[2];
  const float* conv2d_b = (const float*)d_in[3];
  const float* conv1_w  = (const float*)d_in[4];
  const float* conv1_b  = (const float*)d_in[5];
  const float* pool_w   = (const float*)d_in[6];
  float* out = (float*)d_out;

  char* ws = (char*)d_ws;
  signed char* wt      = (signed char*)(ws);               //  75,497,472 B
  signed char* xT      = (signed char*)(ws + 75497472);    //  16,777,216
  u16*         normT   = (u16*)(ws + 92274688);            //  16,777,216
  u16*         out_all = (u16*)(ws + 109051904);           //  67,108,864
  float*       P       = (float*)(ws + 176160768);         //  11,010,048
  u16*         Psum    = (u16*)(ws + 187170816);           //     344,064
  float*       o2part  = (float*)(ws + 187514880);         //   2,752,512
  float*       inp     = (float*)(ws + 190267392);         //     688,128
  float*       pred    = (float*)(ws + 190955520);         //       2,688
  float*       zpage   = (float*)(ws + 190958208);         //       1,024

  float* out_prob = out;                 // 168
  float* out_wc   = out + 168;           // 172032
  float* out_wei  = out + 168 + 172032;  // 172032

  hipLaunchKernelGGL(zero_kernel, dim3(1), dim3(256), 0, stream, zpage);
  hipLaunchKernelGGL(prep_w_kernel, dim3(4096), dim3(256), 0, stream,
                     conv2d_w, (unsigned*)wt);
  hipLaunchKernelGGL(prep_x_kernel, dim3(4096), dim3(256), 0, stream,
                     x, (unsigned*)xT);
  hipLaunchKernelGGL(norm_kernel, dim3(8192), dim3(256), 0, stream, diffW, normT);
  hipLaunchKernelGGL(conv8_kernel, dim3(2048), dim3(256), 0, stream,
                     wt, xT, conv2d_b, (const signed char*)zpage, out_all);
  hipLaunchKernelGGL(p_kernel, dim3(256), dim3(512), 0, stream, out_all, conv1_w, P);
  hipLaunchKernelGGL(psum_kernel, dim3(84), dim3(256), 0, stream, P, Psum);
  hipLaunchKernelGGL(weicum2a_kernel, dim3(128), dim3(256), 0, stream,
                     Psum, normT, o2part);
  hipLaunchKernelGGL(weicum2b_kernel, dim3(32), dim3(256), 0, stream,
                     o2part, conv1_b, out_wc, inp);
  hipLaunchKernelGGL(weipred_kernel, dim3(672), dim3(256), 0, stream,
                     inp, P, pool_w, conv1_b, pred, out_wei);
  hipLaunchKernelGGL(prob_kernel, dim3(1), dim3(256), 0, stream, pred, out_prob);
}

// Round 15
// 672.674 us; speedup vs baseline: 1.0788x; 1.0788x over previous
//
#include <hip/hip_runtime.h>
#include <hip/hip_bf16.h>

typedef unsigned short u16;
typedef __attribute__((ext_vector_type(4))) float f32x4;
typedef __attribute__((ext_vector_type(4))) int i32x4;
typedef __attribute__((ext_vector_type(8))) short bf16x8;

#define NIT 4
#define NCLS 21
#define BS 8
#define CIN 2048
#define COUT 1024
#define WH 1024

#define SX 32.0f
#define SW 3200.0f
#define INVS (1.0f / (SX * SW))

__device__ __forceinline__ u16 f2bf(float f) {
  union { float f; unsigned u; } v; v.f = f;
  unsigned r = v.u + 0x7fffu + ((v.u >> 16) & 1u);
  return (u16)(r >> 16);
}
__device__ __forceinline__ float bf2f(u16 h) {
  union { unsigned u; float f; } v; v.u = ((unsigned)h) << 16;
  return v.f;
}
__device__ __forceinline__ unsigned q8u(float v, float s) {
  float x = v * s;
  x = fminf(fmaxf(x, -127.f), 127.f);
  return (unsigned)(unsigned char)(signed char)__float2int_rn(x);
}

#define GLDS16(gp, lp) __builtin_amdgcn_global_load_lds( \
    (const __attribute__((address_space(1))) unsigned int*)(gp), \
    (__attribute__((address_space(3))) unsigned int*)(lp), 16, 0, 0)

// ---------------- fused prep: blocks [0,4096) prep_w | [4096,8192) prep_x
//                 | [8192,16384) norm | 16384 zero  (all independent, BW-bound)
__global__ void prep_all_kernel(const float* __restrict__ w, unsigned* __restrict__ wt4,
                                const float* __restrict__ x, unsigned* __restrict__ xT4,
                                const float* __restrict__ diffW, u16* __restrict__ normT,
                                float* __restrict__ zpage) {
  __shared__ float ls[9216];                       // 36 KB union
  const int blk = blockIdx.x;
  const int t = threadIdx.x;

  if (blk < 4096) {
    // ---- prep_w: conv2d_w f32 -> wt int8 [it][tap][co][ci], packed u32 stores
    int it = blk >> 10, co = blk & 1023;
    const f32x4* src4 = (const f32x4*)(w + (size_t)(it * 1024 + co) * (CIN * 9));
    for (int chunk = 0; chunk < 2; ++chunk) {
      for (int i = t; i < 2304; i += 256)
        *(f32x4*)&ls[i * 4] = src4[chunk * 2304 + i];
      __syncthreads();
      float r[36];
      #pragma unroll
      for (int j = 0; j < 9; ++j)
        *(f32x4*)&r[j * 4] = *(const f32x4*)&ls[t * 36 + j * 4];
      #pragma unroll
      for (int tap = 0; tap < 9; ++tap) {
        unsigned pk = q8u(r[tap], SW)
                    | (q8u(r[9 + tap], SW) << 8)
                    | (q8u(r[18 + tap], SW) << 16)
                    | (q8u(r[27 + tap], SW) << 24);
        wt4[((((size_t)(it * 9 + tap) * 1024 + co) * CIN + chunk * 1024) >> 2) + t] = pk;
      }
      __syncthreads();
    }
  } else if (blk < 8192) {
    // ---- prep_x: x f32 -> xT int8 [b][p][ci], packed u32 stores
    int bid = blk - 4096;
    int pT = bid & 15, ciT = (bid >> 4) & 31, b = bid >> 9;
    float (*ls2)[65] = (float(*)[65])ls;
    int tr = t >> 6, tc = t & 63;
    const float* xp = x + ((size_t)b * CIN + ciT * 64) * WH + pT * 64;
    #pragma unroll
    for (int r = 0; r < 16; ++r) {
      int ci = r * 4 + tr;
      ls2[ci][tc] = xp[(size_t)ci * WH + tc];
    }
    __syncthreads();
    unsigned* xtp = xT4 + ((((size_t)b * WH + pT * 64) * CIN + ciT * 64) >> 2);
    #pragma unroll
    for (int r = 0; r < 4; ++r) {
      int p = r * 16 + (t >> 4);
      int ci0 = (t & 15) * 4;
      unsigned pk = q8u(ls2[ci0][p], SX)
                  | (q8u(ls2[ci0 + 1][p], SX) << 8)
                  | (q8u(ls2[ci0 + 2][p], SX) << 16)
                  | (q8u(ls2[ci0 + 3][p], SX) << 24);
      xtp[(size_t)p * (CIN >> 2) + (t & 15)] = pk;
    }
  } else if (blk < 16384) {
    // ---- norm: diffW -> normT bf16 (threshold + row-normalize)
    int bid = blk - 8192;
    int b = bid >> 10, m = bid & 1023;
    const f32x4* row4 = (const f32x4*)(diffW + (((size_t)(b * 1024 + m)) << 10));
    f32x4 vv = row4[t];
    float s = 0.f;
    #pragma unroll
    for (int i = 0; i < 4; ++i) {
      vv[i] = (vv[i] > 0.8f) ? vv[i] : 0.f;
      s += vv[i];
    }
    #pragma unroll
    for (int off = 1; off < 64; off <<= 1) s += __shfl_xor(s, off);
    if ((t & 63) == 0) ls[t >> 6] = s;
    __syncthreads();
    float inv = 1.f / (ls[0] + ls[1] + ls[2] + ls[3]);
    ushort4 o;
    o.x = f2bf(vv[0] * inv); o.y = f2bf(vv[1] * inv);
    o.z = f2bf(vv[2] * inv); o.w = f2bf(vv[3] * inv);
    *((ushort4*)(normT + (((size_t)(b * 1024 + m)) << 10)) + t) = o;
  } else {
    zpage[t] = 0.f;
  }
}

// ================ conv implicit GEMM, 256^2 tile, INT8 MFMA — R13 known-best
// Single barrier per K-tile (K=128 i8); A&B staged at +1 into buf p2^1;
// end-of-j vmcnt(0) drain compute-covered; compiler-managed fine lgkmcnt.
__global__ __launch_bounds__(512, 2)
void conv8_kernel(const signed char* __restrict__ wt, const signed char* __restrict__ xT,
                  const float* __restrict__ bias, const signed char* __restrict__ zpage,
                  u16* __restrict__ out_all) {
  const int bid = blockIdx.x;
  const int b = bid & 7;
  const int s = bid >> 3;
  const int g = s >> 2, mt = s & 3;
  const int it = g >> 2;
  const int nt = (int)((0x2130321030213210ULL >> (g * 4)) & 0xFULL);
  const int M0 = mt * 256, N0 = nt * 256;
  const int tid = threadIdx.x, wave = tid >> 6, lane = tid & 63;
  const int wm = wave >> 2, wn = wave & 3;

  const int dil = 6 * (it + 1);
  const int tlo = (8 * nt + 7 < dil) ? 3 : 0;
  const int thi = (8 * nt + dil >= 32) ? 6 : 9;
  const int NT = (thi - tlo) * 16;                 // K-tiles of 128 i8

  __shared__ char lds[2][2][256][128];             // 128 KiB

  const signed char* Aglob = wt + (size_t)it * 9 * COUT * CIN;
  const signed char* Bglob = xT + (size_t)b * WH * CIN;

  const int srow = lane >> 3;
  const int scol16 = (lane & 7) ^ srow;

  const signed char* abase[4]; const signed char* bbase[4];
  unsigned long long vmask = 0ull;
  #pragma unroll
  for (int r = 0; r < 4; ++r) {
    int arow = M0 + r * 64 + wave * 8 + srow;
    abase[r] = Aglob + (size_t)arow * CIN + scol16 * 16;
    int n = N0 + r * 64 + wave * 8 + srow;
    bbase[r] = Bglob + (size_t)n * CIN + scol16 * 16;
    int py0 = n >> 5, px0 = n & 31;
    #pragma unroll
    for (int tap = 0; tap < 9; ++tap) {
      int t3 = (tap * 11) >> 5;
      int py = py0 + (t3 - 1) * dil;
      int px = px0 + (tap - t3 * 3 - 1) * dil;
      if (((unsigned)py < 32u) && ((unsigned)px < 32u))
        vmask |= (1ull << (r * 9 + tap));
    }
  }
  const signed char* zp = zpage + scol16 * 16;

  auto stageA = [&](int jj, int hf, int bb) {
    if (jj >= NT) return;
    int tap = tlo + (jj >> 4);
    size_t uoff = (size_t)tap * (COUT * CIN) + (size_t)((jj & 15) << 7);
    #pragma unroll
    for (int i = 0; i < 2; ++i) {
      int r = hf * 2 + i;
      GLDS16(abase[r] + uoff, &lds[bb][0][hf * 128 + i * 64 + wave * 8][0]);
    }
  };
  auto stageB = [&](int jj, int hf, int bb) {
    if (jj >= NT) return;
    int tap = tlo + (jj >> 4);
    int t3 = (tap * 11) >> 5;
    ptrdiff_t toff = (ptrdiff_t)(((t3 - 1) * 32 + (tap - t3 * 3 - 1)) * dil) * CIN
                   + (ptrdiff_t)((jj & 15) << 7);
    #pragma unroll
    for (int i = 0; i < 2; ++i) {
      int r = hf * 2 + i;
      bool valid = (vmask >> (r * 9 + tap)) & 1ull;
      const signed char* src = valid ? (bbase[r] + toff) : zp;
      GLDS16(src, &lds[bb][1][hf * 128 + i * 64 + wave * 8][0]);
    }
  };

  i32x4 acc[8][4] = {};

  const int l15 = lane & 15;
  const int colx[2] = { (((lane >> 4) ^ (lane & 7)) * 16),
                        (((4 + (lane >> 4)) ^ (lane & 7)) * 16) };
  const int arow_byte = (wm * 128 + l15) * 128;
  const int brow_byte = (wn * 64 + l15) * 128;

  stageA(0, 0, 0); stageA(0, 1, 0);
  stageB(0, 0, 0); stageB(0, 1, 0);
  __builtin_amdgcn_sched_barrier(0);
  asm volatile("s_waitcnt vmcnt(0)" ::: "memory");
  __builtin_amdgcn_s_barrier();
  __builtin_amdgcn_sched_barrier(0);

  for (int j = 0; j < NT; ++j) {
    const int p2 = j & 1;
    const char* Ab = (const char*)&lds[p2][0][0][0];
    const char* Bb = (const char*)&lds[p2][1][0][0];

    i32x4 bfr[4][2];
    #pragma unroll
    for (int nf = 0; nf < 4; ++nf) {
      bfr[nf][0] = *(const i32x4*)(Bb + brow_byte + nf * 2048 + colx[0]);
      bfr[nf][1] = *(const i32x4*)(Bb + brow_byte + nf * 2048 + colx[1]);
    }
    stageA(j + 1, 0, p2 ^ 1);
    stageA(j + 1, 1, p2 ^ 1);
    stageB(j + 1, 0, p2 ^ 1);
    stageB(j + 1, 1, p2 ^ 1);

    __builtin_amdgcn_s_setprio(1);
    #pragma unroll
    for (int m = 0; m < 8; ++m) {
      i32x4 a0 = *(const i32x4*)(Ab + arow_byte + m * 2048 + colx[0]);
      i32x4 a1 = *(const i32x4*)(Ab + arow_byte + m * 2048 + colx[1]);
      #pragma unroll
      for (int nf = 0; nf < 4; ++nf) {
        acc[m][nf] = __builtin_amdgcn_mfma_i32_16x16x64_i8(a0, bfr[nf][0], acc[m][nf], 0, 0, 0);
        acc[m][nf] = __builtin_amdgcn_mfma_i32_16x16x64_i8(a1, bfr[nf][1], acc[m][nf], 0, 0, 0);
      }
    }
    __builtin_amdgcn_s_setprio(0);
    __builtin_amdgcn_sched_barrier(0);
    asm volatile("s_waitcnt vmcnt(0)" ::: "memory");
    __builtin_amdgcn_s_barrier();
    __builtin_amdgcn_sched_barrier(0);
  }

  u16* outp = out_all + (size_t)(it * BS + b) * COUT * WH;
  const float* bias_it = bias + it * COUT;
  #pragma unroll
  for (int mf = 0; mf < 8; ++mf)
    #pragma unroll
    for (int nf = 0; nf < 4; ++nf) {
      int col = N0 + wn * 64 + nf * 16 + l15;
      #pragma unroll
      for (int r = 0; r < 4; ++r) {
        int row = M0 + wm * 128 + mf * 16 + (lane >> 4) * 4 + r;
        float v = (float)acc[mf][nf][r] * INVS + bias_it[row];
        outp[((size_t)row << 10) + col] = f2bf(v);
      }
    }
}

// ---------------- P[it,b,c,k] = sum_d w1[it,c,d]*out[it,b,d,k]  (256 blocks x 512 thr)
__global__ __launch_bounds__(512, 2)
void p_kernel(const u16* __restrict__ out_all, const float* __restrict__ w1,
              float* __restrict__ P) {
  int bidx = blockIdx.x;
  int kch = bidx & 7, sl = bidx >> 3;   // sl = it*8+b
  int it = sl >> 3;
  int t = threadIdx.x;
  int wave = t >> 6, lane = t & 63;
  int g = wave & 3;
  int k = kch * 128 + (wave >> 2) * 64 + lane;
  __shared__ float w1f[21][512];
  const u16* op = out_all + ((size_t)sl << 20) + k;
  const float* w1p = w1 + (size_t)it * NCLS * 1024;
  float acc[6] = {0.f, 0.f, 0.f, 0.f, 0.f, 0.f};
  const int cbase = g * 6;
  for (int h = 0; h < 2; ++h) {
    __syncthreads();
    for (int l = t; l < 21 * 128; l += 512) {
      int c = l >> 7, qq = l & 127;
      *(f32x4*)&w1f[c][qq * 4] = *(const f32x4*)(w1p + (size_t)c * 1024 + h * 512 + qq * 4);
    }
    __syncthreads();
    const u16* oph = op + ((size_t)(h * 512) << 10);
    #pragma unroll 4
    for (int dq = 0; dq < 128; ++dq) {
      float vv[4];
      #pragma unroll
      for (int j = 0; j < 4; ++j) vv[j] = bf2f(oph[(size_t)(dq * 4 + j) << 10]);
      #pragma unroll
      for (int cj = 0; cj < 6; ++cj) {
        int c = cbase + cj; if (c > 20) c = 20;
        f32x4 w4 = *(const f32x4*)&w1f[c][dq * 4];
        acc[cj] = fmaf(w4[0], vv[0], acc[cj]);
        acc[cj] = fmaf(w4[1], vv[1], acc[cj]);
        acc[cj] = fmaf(w4[2], vv[2], acc[cj]);
        acc[cj] = fmaf(w4[3], vv[3], acc[cj]);
      }
    }
  }
  float* Pp = P + (((size_t)sl * NCLS) << 10) + k;
  #pragma unroll
  for (int cj = 0; cj < 6; ++cj) {
    int c = cbase + cj;
    if (c < NCLS) Pp[(size_t)c << 10] = acc[cj];
  }
}

// ---------------- Psum[b][c][k] = sum_it P[it,b,c,k]  (bf16)
__global__ void psum_kernel(const float* __restrict__ P, u16* __restrict__ Psum) {
  int idx = blockIdx.x * 256 + threadIdx.x;   // 21504 = 8*21*128
  int k8 = idx & 127;
  int c = (idx >> 7) % 21;
  int b = idx / (21 * 128);
  float s[8] = {};
  #pragma unroll
  for (int it = 0; it < 4; ++it) {
    const float* pp = P + ((((size_t)(it * 8 + b)) * NCLS + c) << 10) + k8 * 8;
    f32x4 a0 = *(const f32x4*)pp;
    f32x4 a1 = *(const f32x4*)(pp + 4);
    s[0] += a0[0]; s[1] += a0[1]; s[2] += a0[2]; s[3] += a0[3];
    s[4] += a1[0]; s[5] += a1[1]; s[6] += a1[2]; s[7] += a1[3];
  }
  bf16x8 pv;
  #pragma unroll
  for (int j = 0; j < 8; ++j) pv[j] = (short)f2bf(s[j]);
  *(bf16x8*)(Psum + (((size_t)(b * NCLS + c)) << 10) + k8 * 8) = pv;
}

// ---------------- weicum2a: partial o2sum over k-chunk (128 blocks)
__global__ __launch_bounds__(256, 4)
void weicum2a_kernel(const u16* __restrict__ Psum, const u16* __restrict__ normT,
                     float* __restrict__ o2part) {
  int bidx = blockIdx.x;     // b(8) x mch(4) x kch(4)
  int kch = bidx & 3, mch = (bidx >> 2) & 3, b = bidx >> 4;
  int t = threadIdx.x;
  __shared__ u16 ps[21][256];
  for (int l = t; l < 21 * 32; l += 256) {
    int c = l >> 5, q = l & 31;
    *(bf16x8*)&ps[c][q * 8] =
        *(const bf16x8*)(Psum + (((size_t)(b * NCLS + c)) << 10) + kch * 256 + q * 8);
  }
  __syncthreads();
  int m = mch * 256 + t;
  const u16* nr = normT + ((size_t)(b * 1024 + m)) * 1024 + kch * 256;
  float acc[NCLS];
  #pragma unroll
  for (int c = 0; c < NCLS; ++c) acc[c] = 0.f;
  for (int oct = 0; oct < 32; ++oct) {
    bf16x8 nv = *(const bf16x8*)(nr + oct * 8);
    float nf[8];
    #pragma unroll
    for (int j = 0; j < 8; ++j) nf[j] = bf2f((u16)nv[j]);
    #pragma unroll
    for (int c = 0; c < NCLS; ++c) {
      bf16x8 pv = *(const bf16x8*)&ps[c][oct * 8];
      #pragma unroll
      for (int j = 0; j < 8; ++j) acc[c] = fmaf(nf[j], bf2f((u16)pv[j]), acc[c]);
    }
  }
  float* op = o2part + (size_t)bidx * NCLS * 256;
  #pragma unroll
  for (int c = 0; c < NCLS; ++c) op[c * 256 + t] = acc[c];
}

// ---------------- weicum2b: reduce partials + double softmax -> wc_out, inp
__global__ void weicum2b_kernel(const float* __restrict__ o2part, const float* __restrict__ b1,
                                float* __restrict__ wc_out, float* __restrict__ inp) {
  int bidx = blockIdx.x;  // 32 = b(8) x mch(4)
  int mch = bidx & 3, b = bidx >> 2;
  int t = threadIdx.x;
  int m = mch * 256 + t;
  float acc[NCLS];
  #pragma unroll
  for (int c = 0; c < NCLS; ++c) {
    float s = 0.f;
    #pragma unroll
    for (int kch = 0; kch < 4; ++kch)
      s += o2part[((size_t)((b * 4 + mch) * 4 + kch) * NCLS + c) * 256 + t];
    acc[c] = s;
  }
  float mx = -1e30f;
  #pragma unroll
  for (int c = 0; c < NCLS; ++c) {
    float bs = 0.f;
    #pragma unroll
    for (int itp = 0; itp < NIT; ++itp) bs += b1[itp * NCLS + c];
    acc[c] = (acc[c] + bs) * 0.25f;
    mx = fmaxf(mx, acc[c]);
  }
  float s = 0.f;
  #pragma unroll
  for (int c = 0; c < NCLS; ++c) { acc[c] = expf(acc[c] - mx); s += acc[c]; }
  float inv = 1.f / s;
  float* wp = wc_out + (((size_t)b * NCLS) << 10) + m;
  float mx2 = -1e30f;
  #pragma unroll
  for (int c = 0; c < NCLS; ++c) {
    acc[c] *= inv;
    wp[(size_t)c << 10] = acc[c];
    mx2 = fmaxf(mx2, acc[c]);
  }
  float s2 = 0.f;
  #pragma unroll
  for (int c = 0; c < NCLS; ++c) { acc[c] = expf(acc[c] - mx2); s2 += acc[c]; }
  float inv2 = 1.f / s2;
  float* ip = inp + (((size_t)b * NCLS) << 10) + m;
  #pragma unroll
  for (int c = 0; c < NCLS; ++c) ip[(size_t)c << 10] = acc[c] * inv2;
}

// ---------------- per-(it,b,c): wei = softmax_n(inp*exp(pw)); pred = sum_n wei*P + b1
__global__ void weipred_kernel(const float* __restrict__ inp, const float* __restrict__ proj,
                               const float* __restrict__ pool_w, const float* __restrict__ b1,
                               float* __restrict__ pred, float* __restrict__ wei_out) {
  int bid = blockIdx.x;                 // it*168 + b*21 + c
  int it = bid / 168, r = bid % 168;
  int b = r / NCLS, c = r % NCLS;
  int t = threadIdx.x;
  float scale = expf(pool_w[it * NCLS + c]);
  const float* ip = inp + ((size_t)(b * NCLS + c)) * 1024;
  float v[4]; float mx = -1e30f;
  #pragma unroll
  for (int i = 0; i < 4; ++i) { v[i] = ip[t + i * 256] * scale; mx = fmaxf(mx, v[i]); }
  __shared__ float red[4];
  #pragma unroll
  for (int off = 1; off < 64; off <<= 1) mx = fmaxf(mx, __shfl_xor(mx, off));
  if ((t & 63) == 0) red[t >> 6] = mx;
  __syncthreads();
  mx = fmaxf(fmaxf(red[0], red[1]), fmaxf(red[2], red[3]));
  __syncthreads();
  float s = 0.f;
  #pragma unroll
  for (int i = 0; i < 4; ++i) { v[i] = expf(v[i] - mx); s += v[i]; }
  #pragma unroll
  for (int off = 1; off < 64; off <<= 1) s += __shfl_xor(s, off);
  if ((t & 63) == 0) red[t >> 6] = s;
  __syncthreads();
  s = red[0] + red[1] + red[2] + red[3];
  float inv = 1.f / s;
  __syncthreads();
  const float* pj = proj + (((size_t)(it * BS + b)) * NCLS + c) * 1024;
  float ps = 0.f;
  #pragma unroll
  for (int i = 0; i < 4; ++i) {
    float wv = v[i] * inv;
    ps += wv * pj[t + i * 256];
    if (it == NIT - 1) wei_out[((size_t)(b * NCLS + c)) * 1024 + t + i * 256] = wv;
  }
  #pragma unroll
  for (int off = 1; off < 64; off <<= 1) ps += __shfl_xor(ps, off);
  if ((t & 63) == 0) red[t >> 6] = ps;
  __syncthreads();
  if (t == 0) pred[bid] = red[0] + red[1] + red[2] + red[3] + b1[it * NCLS + c];
}

// ---------------- prob = sigmoid(mean_it pred)
__global__ void prob_kernel(const float* __restrict__ pred, float* __restrict__ out) {
  int i = threadIdx.x;
  if (i < BS * NCLS) {
    float s = 0.f;
    #pragma unroll
    for (int it = 0; it < NIT; ++it) s += pred[it * BS * NCLS + i];
    s *= 0.25f;
    out[i] = 1.f / (1.f + expf(-s));
  }
}

extern "C" void kernel_launch(void* const* d_in, const int* in_sizes, int n_in,
                              void* d_out, int out_size, void* d_ws, size_t ws_size,
                              hipStream_t stream) {
  const float* x        = (const float*)d_in[0];
  const float* diffW    = (const float*)d_in[1];
  const float* conv2d_w = (const float*)d_in[2];
  const float* conv2d_b = (const float*)d_in[3];
  const float* conv1_w  = (const float*)d_in[4];
  const float* conv1_b  = (const float*)d_in[5];
  const float* pool_w   = (const float*)d_in[6];
  float* out = (float*)d_out;

  char* ws = (char*)d_ws;
  signed char* wt      = (signed char*)(ws);               //  75,497,472 B
  signed char* xT      = (signed char*)(ws + 75497472);    //  16,777,216
  u16*         normT   = (u16*)(ws + 92274688);            //  16,777,216
  u16*         out_all = (u16*)(ws + 109051904);           //  67,108,864
  float*       P       = (float*)(ws + 176160768);         //  11,010,048
  u16*         Psum    = (u16*)(ws + 187170816);           //     344,064
  float*       o2part  = (float*)(ws + 187514880);         //   2,752,512
  float*       inp     = (float*)(ws + 190267392);         //     688,128
  float*       pred    = (float*)(ws + 190955520);         //       2,688
  float*       zpage   = (float*)(ws + 190958208);         //       1,024

  float* out_prob = out;                 // 168
  float* out_wc   = out + 168;           // 172032
  float* out_wei  = out + 168 + 172032;  // 172032

  hipLaunchKernelGGL(prep_all_kernel, dim3(16385), dim3(256), 0, stream,
                     conv2d_w, (unsigned*)wt, x, (unsigned*)xT, diffW, normT, zpage);
  hipLaunchKernelGGL(conv8_kernel, dim3(512), dim3(512), 0, stream,
                     wt, xT, conv2d_b, (const signed char*)zpage, out_all);
  hipLaunchKernelGGL(p_kernel, dim3(256), dim3(512), 0, stream, out_all, conv1_w, P);
  hipLaunchKernelGGL(psum_kernel, dim3(84), dim3(256), 0, stream, P, Psum);
  hipLaunchKernelGGL(weicum2a_kernel, dim3(128), dim3(256), 0, stream,
                     Psum, normT, o2part);
  hipLaunchKernelGGL(weicum2b_kernel, dim3(32), dim3(256), 0, stream,
                     o2part, conv1_b, out_wc, inp);
  hipLaunchKernelGGL(weipred_kernel, dim3(672), dim3(256), 0, stream,
                     inp, P, pool_w, conv1_b, pred, out_wei);
  hipLaunchKernelGGL(prob_kernel, dim3(1), dim3(256), 0, stream, pred, out_prob);
}